// Round 1
// baseline (645.241 us; speedup 1.0000x reference)
//
#include <hip/hip_runtime.h>
#include <hip/hip_bf16.h>

#define N_PTS 8192
#define KNN 8

// ---------------------------------------------------------------------------
// KNN: for each query point, indices of 8 nearest (incl. self).
// Block = 256 threads = 32 queries x 8 scan-partitions. Positions staged in
// LDS in 4 tiles of 2048 (float4). Distances in f64: f32 subtraction is exact
// in f64, so ranking matches the true ordering to ~1e-16 (downstream is
// permutation-invariant over K, only the set matters).
// ---------------------------------------------------------------------------
__global__ __launch_bounds__(256) void knn_kernel(const float* __restrict__ pos,
                                                  int* __restrict__ idxo)
{
    __shared__ float4 spos[2048];        // 32 KB
    __shared__ double mdist[32][64];     // 16 KB
    __shared__ int    midx[32][64];      // 8 KB

    const int tid = threadIdx.x;
    const int q   = tid >> 3;            // local query 0..31
    const int s   = tid & 7;             // partition 0..7
    const int batch = blockIdx.x >> 8;   // 256 blocks per batch
    const int qglob = (blockIdx.x & 255) * 32 + q;
    const float* bpos = pos + (long)batch * N_PTS * 3;

    const double qx = (double)bpos[qglob * 3 + 0];
    const double qy = (double)bpos[qglob * 3 + 1];
    const double qz = (double)bpos[qglob * 3 + 2];

    double bd[8]; int bi[8];
#pragma unroll
    for (int i = 0; i < 8; ++i) { bd[i] = 1e300; bi[i] = -1; }
    double dmax = 1e300; int imax = 0;

    for (int tile = 0; tile < 4; ++tile) {
        const int tbase = tile * 2048;
        for (int p = tid; p < 2048; p += 256) {
            const int gp = tbase + p;
            spos[p] = make_float4(bpos[gp * 3], bpos[gp * 3 + 1], bpos[gp * 3 + 2], 0.f);
        }
        __syncthreads();
        for (int i = 0; i < 256; ++i) {
            const int p = i * 8 + s;     // 8 consecutive float4 per wave: conflict-free broadcast
            const float4 c = spos[p];
            const double dx = (double)c.x - qx;
            const double dy = (double)c.y - qy;
            const double dz = (double)c.z - qz;
            const double d2 = dx * dx + dy * dy + dz * dz;
            if (d2 < dmax) {
                bd[imax] = d2; bi[imax] = tbase + p;
                dmax = bd[0]; imax = 0;
#pragma unroll
                for (int t = 1; t < 8; ++t)
                    if (bd[t] > dmax) { dmax = bd[t]; imax = t; }
            }
        }
        __syncthreads();
    }
#pragma unroll
    for (int t = 0; t < 8; ++t) { mdist[q][s * 8 + t] = bd[t]; midx[q][s * 8 + t] = bi[t]; }
    __syncthreads();

    if (tid < 32) {                      // merge 8 partial top-8 lists per query
        double fb[8]; int fi[8];
#pragma unroll
        for (int t = 0; t < 8; ++t) { fb[t] = mdist[tid][t]; fi[t] = midx[tid][t]; }
        double fm = fb[0]; int fim = 0;
#pragma unroll
        for (int t = 1; t < 8; ++t) if (fb[t] > fm) { fm = fb[t]; fim = t; }
        for (int u = 8; u < 64; ++u) {
            const double d = mdist[tid][u];
            if (d < fm) {
                fb[fim] = d; fi[fim] = midx[tid][u];
                fm = fb[0]; fim = 0;
#pragma unroll
                for (int t = 1; t < 8; ++t) if (fb[t] > fm) { fm = fb[t]; fim = t; }
            }
        }
        const int qg = (blockIdx.x & 255) * 32 + tid;
#pragma unroll
        for (int t = 0; t < 8; ++t)
            idxo[((long)batch * N_PTS + qg) * KNN + t] = fi[t];
    }
}

// ---------------------------------------------------------------------------
// fp32 SGEMM: C[M,N] = A[M,K] * B[K,N] (+ bias[N]). 64x64 tile, BK=16,
// 256 threads, 4x4 micro-tile per thread. M,N%64==0, K%16==0 for our shapes.
// ---------------------------------------------------------------------------
__global__ __launch_bounds__(256) void sgemm64(const float* __restrict__ A,
                                               const float* __restrict__ B,
                                               const float* __restrict__ bias,
                                               float* __restrict__ C,
                                               int M, int N, int Kd)
{
    __shared__ float As[16][68];   // [k][m] transposed, +4 pad
    __shared__ float Bs[16][64];   // [k][n]

    const int tid = threadIdx.x;
    const int tx = tid & 15;
    const int ty = tid >> 4;
    const int bx = blockIdx.x;
    const int by = blockIdx.y;

    const int arow  = tid >> 2;          // 0..63
    const int acol4 = (tid & 3) * 4;     // 0,4,8,12
    const int brow  = tid >> 4;          // 0..15
    const int bcol4 = (tid & 15) * 4;    // 0..60

    const float* Ap = A + (long)(by * 64 + arow) * Kd + acol4;
    const float* Bp = B + (long)brow * N + bx * 64 + bcol4;

    float acc[4][4] = {{0.f}};

    for (int kt = 0; kt < Kd; kt += 16) {
        const float4 av = *(const float4*)(Ap + kt);
        const float4 bv = *(const float4*)(Bp + (long)kt * N);
        As[acol4 + 0][arow] = av.x;
        As[acol4 + 1][arow] = av.y;
        As[acol4 + 2][arow] = av.z;
        As[acol4 + 3][arow] = av.w;
        *(float4*)&Bs[brow][bcol4] = bv;
        __syncthreads();
#pragma unroll
        for (int k = 0; k < 16; ++k) {
            const float4 a = *(const float4*)&As[k][ty * 4];
            const float4 b = *(const float4*)&Bs[k][tx * 4];
            acc[0][0] = fmaf(a.x, b.x, acc[0][0]);
            acc[0][1] = fmaf(a.x, b.y, acc[0][1]);
            acc[0][2] = fmaf(a.x, b.z, acc[0][2]);
            acc[0][3] = fmaf(a.x, b.w, acc[0][3]);
            acc[1][0] = fmaf(a.y, b.x, acc[1][0]);
            acc[1][1] = fmaf(a.y, b.y, acc[1][1]);
            acc[1][2] = fmaf(a.y, b.z, acc[1][2]);
            acc[1][3] = fmaf(a.y, b.w, acc[1][3]);
            acc[2][0] = fmaf(a.z, b.x, acc[2][0]);
            acc[2][1] = fmaf(a.z, b.y, acc[2][1]);
            acc[2][2] = fmaf(a.z, b.z, acc[2][2]);
            acc[2][3] = fmaf(a.z, b.w, acc[2][3]);
            acc[3][0] = fmaf(a.w, b.x, acc[3][0]);
            acc[3][1] = fmaf(a.w, b.y, acc[3][1]);
            acc[3][2] = fmaf(a.w, b.z, acc[3][2]);
            acc[3][3] = fmaf(a.w, b.w, acc[3][3]);
        }
        __syncthreads();
    }

    const int row = by * 64 + ty * 4;
    const int col = bx * 64 + tx * 4;
    float4 bb = make_float4(0.f, 0.f, 0.f, 0.f);
    if (bias) bb = *(const float4*)(bias + col);
#pragma unroll
    for (int i = 0; i < 4; ++i) {
        float4 o;
        o.x = acc[i][0] + bb.x;
        o.y = acc[i][1] + bb.y;
        o.z = acc[i][2] + bb.z;
        o.w = acc[i][3] + bb.w;
        *(float4*)&C[(long)(row + i) * N + col] = o;
    }
}

// ---------------------------------------------------------------------------
// Fused KNN attention. One wave per query. Phase 1: lane=(h,k) computes one
// q.k dot (64-long, float4 loads), shfl softmax over k-groups of 8.
// Phase 2: lane=d, coalesced v gather, weighted sum, write out.
// outp may alias qall (q fully consumed before the barrier; one wave per row).
// ---------------------------------------------------------------------------
__global__ __launch_bounds__(256) void attn_kernel(const float* qall,
                                                   const float* __restrict__ kvall,
                                                   const int* __restrict__ idxp,
                                                   float* outp)
{
    __shared__ float attn_s[4][8][8];
    const int wave = threadIdx.x >> 6;
    const int lane = threadIdx.x & 63;
    const int g = blockIdx.x * 4 + wave;     // query 0..16383
    const int b = g >> 13;
    const int* myidx = idxp + (long)g * 8;

    const int h = lane >> 3;
    const int k = lane & 7;
    const int j = myidx[k];
    const float* qrow = qall + (long)g * 512 + h * 64;
    const float* krow = kvall + ((long)(b * N_PTS + j)) * 1024 + h * 64;

    float dot = 0.f;
#pragma unroll
    for (int d4 = 0; d4 < 64; d4 += 4) {
        const float4 qv = *(const float4*)(qrow + d4);
        const float4 kv = *(const float4*)(krow + d4);
        dot = fmaf(qv.x, kv.x, dot);
        dot = fmaf(qv.y, kv.y, dot);
        dot = fmaf(qv.z, kv.z, dot);
        dot = fmaf(qv.w, kv.w, dot);
    }
    dot *= 0.125f;                            // DH^-0.5

    float m = dot;
#pragma unroll
    for (int off = 1; off < 8; off <<= 1)
        m = fmaxf(m, __shfl_xor(m, off, 8));
    const float e = __expf(dot - m);
    float ssum = e;
#pragma unroll
    for (int off = 1; off < 8; off <<= 1)
        ssum += __shfl_xor(ssum, off, 8);
    attn_s[wave][h][k] = e / ssum;
    __syncthreads();                          // also drains q loads before aliased writes

    const int d = lane;
    float o[8] = {0.f, 0.f, 0.f, 0.f, 0.f, 0.f, 0.f, 0.f};
#pragma unroll
    for (int kk = 0; kk < 8; ++kk) {
        const int jj = myidx[kk];
        const float* vrow = kvall + ((long)(b * N_PTS + jj)) * 1024 + 512 + d;
#pragma unroll
        for (int hh = 0; hh < 8; ++hh)
            o[hh] = fmaf(attn_s[wave][hh][kk], vrow[hh * 64], o[hh]);
    }
    float* orow = outp + (long)g * 512 + d;
#pragma unroll
    for (int hh = 0; hh < 8; ++hh)
        orow[hh * 64] = o[hh];
}

// ---------------------------------------------------------------------------
extern "C" void kernel_launch(void* const* d_in, const int* in_sizes, int n_in,
                              void* d_out, int out_size, void* d_ws, size_t ws_size,
                              hipStream_t stream)
{
    const float* x    = (const float*)d_in[0];  // [2,8192,256]
    const float* pos  = (const float*)d_in[1];  // [2,8192,3]
    const float* Wq   = (const float*)d_in[2];  // [256,512]
    const float* Wkv  = (const float*)d_in[3];  // [256,1024]
    const float* Wout = (const float*)d_in[4];  // [512,256]
    const float* bout = (const float*)d_in[5];  // [256]
    float* out = (float*)d_out;                 // [2,8192,256] f32

    // workspace layout (96.5 MB total):
    int*   idxp  = (int*)d_ws;                       // 131072 ints (512 KB)
    float* qall  = (float*)d_ws + 131072;            // 16384x512 f32 (32 MB)
    float* kvall = qall + (long)16384 * 512;         // 16384x1024 f32 (64 MB)

    const int M = 16384;

    knn_kernel<<<512, 256, 0, stream>>>(pos, idxp);
    sgemm64<<<dim3(512 / 64, M / 64), 256, 0, stream>>>(x, Wq, nullptr, qall, M, 512, 256);
    sgemm64<<<dim3(1024 / 64, M / 64), 256, 0, stream>>>(x, Wkv, nullptr, kvall, M, 1024, 256);
    attn_kernel<<<M / 4, 256, 0, stream>>>(qall, kvall, idxp, qall);   // in-place over qall
    sgemm64<<<dim3(256 / 64, M / 64), 256, 0, stream>>>(qall, Wout, bout, out, M, 256, 512);
}

// Round 2
// 564.804 us; speedup vs baseline: 1.1424x; 1.1424x over previous
//
#include <hip/hip_runtime.h>
#include <hip/hip_bf16.h>

#define N_PTS 8192
#define KNN 8

// ---------------------------------------------------------------------------
// KNN: for each query point, indices of 8 nearest (incl. self).
// Block = 256 threads = 32 queries x 8 scan-partitions. Positions staged in
// LDS in 4 tiles of 2048 (float4). Distances in f32 via EXACT-DIFFERENCE form
// (dx*dx+dy*dy+dz*dz, ~2ulp relative error) -- 30x more accurate than the
// reference's cancellation-prone |a|^2+|b|^2-2ab f32 formula, whose ~1e-6
// absolute noise provably did not flip any selection on this dataset
// (round-1 f64-exact run passed at 9.8e-4 absmax).
// ---------------------------------------------------------------------------
__global__ __launch_bounds__(256) void knn_kernel(const float* __restrict__ pos,
                                                  int* __restrict__ idxo)
{
    __shared__ float4 spos[2048];        // 32 KB
    __shared__ float  mdist[32][64];     // 8 KB
    __shared__ int    midx[32][64];      // 8 KB

    const int tid = threadIdx.x;
    const int q   = tid >> 3;            // local query 0..31
    const int s   = tid & 7;             // partition 0..7
    const int batch = blockIdx.x >> 8;   // 256 blocks per batch
    const int qglob = (blockIdx.x & 255) * 32 + q;
    const float* bpos = pos + (long)batch * N_PTS * 3;

    const float qx = bpos[qglob * 3 + 0];
    const float qy = bpos[qglob * 3 + 1];
    const float qz = bpos[qglob * 3 + 2];

    float bd[8]; int bi[8];
#pragma unroll
    for (int i = 0; i < 8; ++i) { bd[i] = 3.0e38f; bi[i] = -1; }
    float dmax = 3.0e38f; int imax = 0;

    for (int tile = 0; tile < 4; ++tile) {
        const int tbase = tile * 2048;
        for (int p = tid; p < 2048; p += 256) {
            const int gp = tbase + p;
            spos[p] = make_float4(bpos[gp * 3], bpos[gp * 3 + 1], bpos[gp * 3 + 2], 0.f);
        }
        __syncthreads();
        for (int i = 0; i < 256; ++i) {
            const int p = i * 8 + s;     // 8 consecutive float4 per wave
            const float4 c = spos[p];
            const float dx = c.x - qx;
            const float dy = c.y - qy;
            const float dz = c.z - qz;
            const float d2 = fmaf(dx, dx, fmaf(dy, dy, dz * dz));
            if (d2 < dmax) {
                bd[imax] = d2; bi[imax] = tbase + p;
                dmax = bd[0]; imax = 0;
#pragma unroll
                for (int t = 1; t < 8; ++t)
                    if (bd[t] > dmax) { dmax = bd[t]; imax = t; }
            }
        }
        __syncthreads();
    }
#pragma unroll
    for (int t = 0; t < 8; ++t) { mdist[q][s * 8 + t] = bd[t]; midx[q][s * 8 + t] = bi[t]; }
    __syncthreads();

    if (tid < 32) {                      // merge 8 partial top-8 lists per query
        float fb[8]; int fi[8];
#pragma unroll
        for (int t = 0; t < 8; ++t) { fb[t] = mdist[tid][t]; fi[t] = midx[tid][t]; }
        float fm = fb[0]; int fim = 0;
#pragma unroll
        for (int t = 1; t < 8; ++t) if (fb[t] > fm) { fm = fb[t]; fim = t; }
        for (int u = 8; u < 64; ++u) {
            const float d = mdist[tid][u];
            if (d < fm) {
                fb[fim] = d; fi[fim] = midx[tid][u];
                fm = fb[0]; fim = 0;
#pragma unroll
                for (int t = 1; t < 8; ++t) if (fb[t] > fm) { fm = fb[t]; fim = t; }
            }
        }
        const int qg = (blockIdx.x & 255) * 32 + tid;
#pragma unroll
        for (int t = 0; t < 8; ++t)
            idxo[((long)batch * N_PTS + qg) * KNN + t] = fi[t];
    }
}

// ---------------------------------------------------------------------------
// fp32 SGEMM: C[M,N] = A[M,K] * B[K,N] (+ bias[N]). 128x128 tile, BK=16,
// 256 threads, 8x8 micro-tile (2x2 blocks of float4): 64 fma per 4 ds_read_b128.
// Requires M,N % 128 == 0, K % 16 == 0 (holds for all three calls).
// ---------------------------------------------------------------------------
__global__ __launch_bounds__(256) void sgemm128(const float* __restrict__ A,
                                                const float* __restrict__ B,
                                                const float* __restrict__ bias,
                                                float* __restrict__ C,
                                                int M, int N, int Kd)
{
    __shared__ float As[16][132];   // [k][m] transposed, +4 pad (8448 B)
    __shared__ float Bs[16][128];   // [k][n] (8192 B)

    const int tid = threadIdx.x;
    const int tx = tid & 15;            // 0..15 -> col groups
    const int ty = tid >> 4;            // 0..15 -> row groups
    const int bx = blockIdx.x;
    const int by = blockIdx.y;

    // A staging: 128 rows x 16 k. 2048 f32 / 256 thr = 8 f32 (2 float4) each.
    const int arow  = tid >> 1;          // 0..127
    const int acol8 = (tid & 1) * 8;     // 0 or 8
    // B staging: 16 k x 128 cols. 8 f32 (2 float4) each.
    const int brow  = tid >> 4;          // 0..15
    const int bcol  = (tid & 15) * 4;    // 0..60

    const float* Ap = A + (long)(by * 128 + arow) * Kd + acol8;
    const float* Bp = B + (long)brow * N + bx * 128 + bcol;

    float acc[8][8];
#pragma unroll
    for (int i = 0; i < 8; ++i)
#pragma unroll
        for (int j = 0; j < 8; ++j) acc[i][j] = 0.f;

    for (int kt = 0; kt < Kd; kt += 16) {
        const float4 av0 = *(const float4*)(Ap + kt);
        const float4 av1 = *(const float4*)(Ap + kt + 4);
        const float4 bv0 = *(const float4*)(Bp + (long)kt * N);
        const float4 bv1 = *(const float4*)(Bp + (long)kt * N + 64);
        As[acol8 + 0][arow] = av0.x;
        As[acol8 + 1][arow] = av0.y;
        As[acol8 + 2][arow] = av0.z;
        As[acol8 + 3][arow] = av0.w;
        As[acol8 + 4][arow] = av1.x;
        As[acol8 + 5][arow] = av1.y;
        As[acol8 + 6][arow] = av1.z;
        As[acol8 + 7][arow] = av1.w;
        *(float4*)&Bs[brow][bcol] = bv0;
        *(float4*)&Bs[brow][bcol + 64] = bv1;
        __syncthreads();
#pragma unroll
        for (int k = 0; k < 16; ++k) {
            const float4 a0 = *(const float4*)&As[k][ty * 4];
            const float4 a1 = *(const float4*)&As[k][ty * 4 + 64];
            const float4 b0 = *(const float4*)&Bs[k][tx * 4];
            const float4 b1 = *(const float4*)&Bs[k][tx * 4 + 64];
            const float ar[8] = {a0.x, a0.y, a0.z, a0.w, a1.x, a1.y, a1.z, a1.w};
            const float br[8] = {b0.x, b0.y, b0.z, b0.w, b1.x, b1.y, b1.z, b1.w};
#pragma unroll
            for (int i = 0; i < 8; ++i)
#pragma unroll
                for (int j = 0; j < 8; ++j)
                    acc[i][j] = fmaf(ar[i], br[j], acc[i][j]);
        }
        __syncthreads();
    }

    // epilogue: rows by*128 + ty*4 + i (+64), cols bx*128 + tx*4 (+64)
    float4 bb0 = make_float4(0.f, 0.f, 0.f, 0.f);
    float4 bb1 = bb0;
    if (bias) {
        bb0 = *(const float4*)(bias + bx * 128 + tx * 4);
        bb1 = *(const float4*)(bias + bx * 128 + tx * 4 + 64);
    }
#pragma unroll
    for (int ih = 0; ih < 2; ++ih) {
#pragma unroll
        for (int i = 0; i < 4; ++i) {
            const int row = by * 128 + ty * 4 + ih * 64 + i;
            float* crow = C + (long)row * N + bx * 128;
            float4 o0, o1;
            o0.x = acc[ih * 4 + i][0] + bb0.x;
            o0.y = acc[ih * 4 + i][1] + bb0.y;
            o0.z = acc[ih * 4 + i][2] + bb0.z;
            o0.w = acc[ih * 4 + i][3] + bb0.w;
            o1.x = acc[ih * 4 + i][4] + bb1.x;
            o1.y = acc[ih * 4 + i][5] + bb1.y;
            o1.z = acc[ih * 4 + i][6] + bb1.z;
            o1.w = acc[ih * 4 + i][7] + bb1.w;
            *(float4*)(crow + tx * 4) = o0;
            *(float4*)(crow + tx * 4 + 64) = o1;
        }
    }
}

// ---------------------------------------------------------------------------
// Fused KNN attention. One wave per query. Phase 1: lane=(h,k) computes one
// q.k dot (64-long, float4 loads), shfl softmax over k-groups of 8.
// Phase 2: lane=d, coalesced v gather, weighted sum, write out.
// outp may alias qall (q fully consumed before the barrier; one wave per row).
// ---------------------------------------------------------------------------
__global__ __launch_bounds__(256) void attn_kernel(const float* qall,
                                                   const float* __restrict__ kvall,
                                                   const int* __restrict__ idxp,
                                                   float* outp)
{
    __shared__ float attn_s[4][8][8];
    const int wave = threadIdx.x >> 6;
    const int lane = threadIdx.x & 63;
    const int g = blockIdx.x * 4 + wave;     // query 0..16383
    const int b = g >> 13;
    const int* myidx = idxp + (long)g * 8;

    const int h = lane >> 3;
    const int k = lane & 7;
    const int j = myidx[k];
    const float* qrow = qall + (long)g * 512 + h * 64;
    const float* krow = kvall + ((long)(b * N_PTS + j)) * 1024 + h * 64;

    float dot = 0.f;
#pragma unroll
    for (int d4 = 0; d4 < 64; d4 += 4) {
        const float4 qv = *(const float4*)(qrow + d4);
        const float4 kv = *(const float4*)(krow + d4);
        dot = fmaf(qv.x, kv.x, dot);
        dot = fmaf(qv.y, kv.y, dot);
        dot = fmaf(qv.z, kv.z, dot);
        dot = fmaf(qv.w, kv.w, dot);
    }
    dot *= 0.125f;                            // DH^-0.5

    float m = dot;
#pragma unroll
    for (int off = 1; off < 8; off <<= 1)
        m = fmaxf(m, __shfl_xor(m, off, 8));
    const float e = __expf(dot - m);
    float ssum = e;
#pragma unroll
    for (int off = 1; off < 8; off <<= 1)
        ssum += __shfl_xor(ssum, off, 8);
    attn_s[wave][h][k] = e / ssum;
    __syncthreads();                          // also drains q loads before aliased writes

    const int d = lane;
    float o[8] = {0.f, 0.f, 0.f, 0.f, 0.f, 0.f, 0.f, 0.f};
#pragma unroll
    for (int kk = 0; kk < 8; ++kk) {
        const int jj = myidx[kk];
        const float* vrow = kvall + ((long)(b * N_PTS + jj)) * 1024 + 512 + d;
#pragma unroll
        for (int hh = 0; hh < 8; ++hh)
            o[hh] = fmaf(attn_s[wave][hh][kk], vrow[hh * 64], o[hh]);
    }
    float* orow = outp + (long)g * 512 + d;
#pragma unroll
    for (int hh = 0; hh < 8; ++hh)
        orow[hh * 64] = o[hh];
}

// ---------------------------------------------------------------------------
extern "C" void kernel_launch(void* const* d_in, const int* in_sizes, int n_in,
                              void* d_out, int out_size, void* d_ws, size_t ws_size,
                              hipStream_t stream)
{
    const float* x    = (const float*)d_in[0];  // [2,8192,256]
    const float* pos  = (const float*)d_in[1];  // [2,8192,3]
    const float* Wq   = (const float*)d_in[2];  // [256,512]
    const float* Wkv  = (const float*)d_in[3];  // [256,1024]
    const float* Wout = (const float*)d_in[4];  // [512,256]
    const float* bout = (const float*)d_in[5];  // [256]
    float* out = (float*)d_out;                 // [2,8192,256] f32

    // workspace layout (96.5 MB total):
    int*   idxp  = (int*)d_ws;                       // 131072 ints (512 KB)
    float* qall  = (float*)d_ws + 131072;            // 16384x512 f32 (32 MB)
    float* kvall = qall + (long)16384 * 512;         // 16384x1024 f32 (64 MB)

    const int M = 16384;

    knn_kernel<<<512, 256, 0, stream>>>(pos, idxp);
    sgemm128<<<dim3(512 / 128, M / 128), 256, 0, stream>>>(x, Wq, nullptr, qall, M, 512, 256);
    sgemm128<<<dim3(1024 / 128, M / 128), 256, 0, stream>>>(x, Wkv, nullptr, kvall, M, 1024, 256);
    attn_kernel<<<M / 4, 256, 0, stream>>>(qall, kvall, idxp, qall);   // in-place over qall
    sgemm128<<<dim3(256 / 128, M / 128), 256, 0, stream>>>(qall, Wout, bout, out, M, 256, 512);
}